// Round 1
// 119.680 us; speedup vs baseline: 1.0036x; 1.0036x over previous
//
#include <hip/hip_runtime.h>

// Fully-fused bior3.5 DWT, J=3, zero-padding. NBLK=8 tiles/row, 8 blocks/CU
// (100% wave occupancy), K=8 register blocking, XOR-swizzled LDS, 4 barriers.
//
// R6 changes vs R5-fixed baseline (118.8/120.1 us):
//  (1) XCD-aware (tile,row) remap: dispatch id = bx + 8*by, XCD ~ id%8 = bx.
//      Old mapping put the 8 tiles of one row on 8 DIFFERENT XCDs, so the
//      ~632B staging halos at each tile boundary were HBM-fetched twice
//      (~4.5 MB total). New: row = bx*128 + (by>>3), tile = by&7 -> all 8
//      tiles of a row share one XCD and are dispatch-adjacent -> halo L2-hits.
//  (2) lgkm-only barriers: __syncthreads drains vmcnt(0) too; at P4->P5 that
//      stalls on the hi1/hi2 global stores which nothing re-reads. Every
//      barrier here only needs LDS ordering (global loads are consumed by
//      register dependency before their ds_write). Raw s_barrier + manual
//      s_waitcnt lgkmcnt(0), memory-clobber sandwiched.
//  (3) nontemporal output stores (evict-first) so the 67 MB write stream
//      doesn't displace the halo lines in L2. x loads stay cached.
//
// LDS (13.3 KB/block):
//   xs[2208]: P1-P2 staged x (+halo). P3+: hi1 stash [0,span1),
//             lo2 [1088,1648), hi2 stash [1664,1664+span2).
//   l1[1120]: P2-P3 lo1 coeffs (pad 12). P4+: lo3 [0,span3), hi3 [272,..).
//
// R5 bug fix retained: c2s forced EVEN (T2=513 odd => B*T2 may be odd), else
// D3 becomes odd and p3 can reach 3 -> L3 window overruns w[28]. Parity
// static_asserts keep a retile from compiling wrong.

#define FILT_LEN 12
#define ROWS  1024
#define N1    16384
#define O1    8197
#define O2    4104
#define O3    2057
#define NBLK  8
#define T1    1025
#define T2    513
#define T3    258
#define NTHR  256

#define XCAP    2208     // floats (552 float4)
#define L1CAP   1120
#define LO2_OFF 1088     // in xs; region size LO2SZ
#define LO2SZ   560
#define HB2_OFF 1664     // in xs
#define HI3_OFF 272      // in l1

constexpr int cmin(int a, int b) { return a < b ? a : b; }
constexpr int cmax(int a, int b) { return a > b ? a : b; }

__device__ __forceinline__ int sw4(int f4) { return f4 ^ ((f4 >> 3) & 7); }
__device__ __forceinline__ float4 ld4(const float* p, int f4) {
    return reinterpret_cast<const float4*>(p)[sw4(f4)];
}
__device__ __forceinline__ void st4(float* p, int f4, float4 v) {
    reinterpret_cast<float4*>(p)[sw4(f4)] = v;
}
__device__ __forceinline__ float ldss(const float* p, int j) {
    return p[(sw4(j >> 2) << 2) | (j & 3)];
}
__device__ __forceinline__ void stss(float* p, int j, float v) {
    p[(sw4(j >> 2) << 2) | (j & 3)] = v;
}

// Barrier with LDS-only drain. __syncthreads would add vmcnt(0): at P4->P5
// that waits for the hi1/hi2 global stores to retire, pure stall. Correctness:
// every inter-phase dependency in this kernel is through LDS; global loads are
// consumed (by ds_write data deps, compiler-inserted vmcnt) before the barrier.
__device__ __forceinline__ void bar_lgkm() {
    asm volatile("s_waitcnt lgkmcnt(0)" ::: "memory");
    __builtin_amdgcn_s_barrier();
    asm volatile("" ::: "memory");
}

__device__ __forceinline__ void ntst(float* p, float v) {
    __builtin_nontemporal_store(v, p);
}

__device__ __forceinline__ constexpr float h0tap(int i) {
    constexpr float H[FILT_LEN] = {
        -0.013810679320049757f, 0.04143203796014927f, 0.052480581416189075f,
        -0.26792717880896527f, -0.07181553246425873f, 0.966747552403483f,
        0.966747552403483f, -0.07181553246425873f, -0.26792717880896527f,
        0.052480581416189075f, 0.04143203796014927f, -0.013810679320049757f};
    return H[i];
}
__device__ __forceinline__ constexpr float h1tap(int i) {
    return h0tap(FILT_LEN - 1 - i) * ((i & 1) ? 1.0f : -1.0f);
}

template<int B>
struct Cfg {
    static constexpr int s1 = B * T1, e1 = cmin(s1 + T1, O1);
    static constexpr int s2 = B * T2, e2 = cmin(s2 + T2, O2);
    static constexpr int s3 = B * T3, e3 = cmin(s3 + T3, O3);
    static constexpr int c2s = cmax(0, cmin(s2, 2 * s3 - 10)) & ~1;  // even!
    static constexpr int c2e = cmin(O2, cmax(e2, 2 * e3));
    static constexpr int c1s = cmax(0, cmin(s1, 2 * c2s - 10)) & ~1;  // even
    static constexpr int c1e = cmin(O1, cmax(e1, 2 * c2e));
    static constexpr int span1 = c1e - c1s;     // <= 1078
    static constexpr int span2 = c2e - c2s;     // <= 534
    static constexpr int span3 = e3 - s3;       // <= 258
    static constexpr int xbase = 2 * c1s - 12;  // mult of 4
    static constexpr int D2 = 2 * c2s - 10 - c1s + 12;   // even, >=0
    static constexpr int ab2 = D2 & ~3, p2 = D2 & 3;     // p2 in {0,2}
    static constexpr int D3 = 2 * s3 - 10 - c2s + 12;    // even, >=0
    static constexpr int ab3 = D3 & ~3, p3 = D3 & 3;     // p3 in {0,2}
    static constexpr int zt1 = L1CAP - (12 + span1);
    static constexpr int zt2 = LO2SZ - (12 + span2);
    static constexpr int o1s = s1 - c1s, o1e = e1 - c1s;
    static constexpr int o2s = s2 - c2s, o2e = e2 - c2s;

    static_assert(D2 >= 0 && D3 >= 0, "pad origin");
    static_assert((D2 & 1) == 0 && (D3 & 1) == 0, "window parity (R5 bug)");
    static_assert(p2 <= 2 && p3 <= 2, "window shift fits 28-float window");
    static_assert((xbase & 3) == 0, "x staging alignment");
    static_assert(zt1 >= 0 && zt1 <= NTHR, "l1 tail zero in one pass");
    static_assert(zt2 >= 0 && zt2 <= NTHR, "lo2 tail zero in one pass");
    static_assert(span1 <= 8 * NTHR && span2 <= 8 * NTHR && span3 <= 8 * NTHR,
                  "single K=8 pass");
    static_assert(2 * (((span1 - 1) / 8) * 8) + 25 + 2 < XCAP, "L1 window read");
    static_assert(2 * (((span2 - 1) / 8) * 8) + ab2 + 25 + p2 < L1CAP, "L2 window read");
    static_assert(2 * (((span3 - 1) / 8) * 8) + ab3 + 25 + p3 < LO2SZ, "L3 window read");
    static_assert(span1 <= LO2_OFF, "hi1 stash fits");
    static_assert(HB2_OFF + span2 <= XCAP, "hi2 stash fits");
    static_assert(HI3_OFF + span3 <= L1CAP, "hi3 stash fits");
    static_assert(HI3_OFF >= span3, "lo3/hi3 disjoint");
};

template<int B>
__device__ __forceinline__ void body(
    const float* __restrict__ xrow,
    float* __restrict__ lo3r, float* __restrict__ hi1r,
    float* __restrict__ hi2r, float* __restrict__ hi3r,
    float* __restrict__ xs, float* __restrict__ l1, const int tid)
{
    using C = Cfg<B>;

    // ---------- P1: stage x (swizzled), zero l1 pads ----------
    if constexpr (C::xbase >= 0 && C::xbase + XCAP <= N1) {
        st4(xs, tid,       *reinterpret_cast<const float4*>(xrow + C::xbase + 4 * tid));
        st4(xs, tid + 256, *reinterpret_cast<const float4*>(xrow + C::xbase + 1024 + 4 * tid));
        if (tid < XCAP / 4 - 512)
            st4(xs, tid + 512, *reinterpret_cast<const float4*>(xrow + C::xbase + 2048 + 4 * tid));
    } else {
        for (int i = tid; i < XCAP / 4; i += NTHR) {
            const int g0 = C::xbase + 4 * i;
            float4 v;
            if (g0 >= 0 && g0 + 4 <= N1) {
                v = *reinterpret_cast<const float4*>(xrow + g0);
            } else {
                v.x = ((unsigned)(g0 + 0) < (unsigned)N1) ? xrow[g0 + 0] : 0.f;
                v.y = ((unsigned)(g0 + 1) < (unsigned)N1) ? xrow[g0 + 1] : 0.f;
                v.z = ((unsigned)(g0 + 2) < (unsigned)N1) ? xrow[g0 + 2] : 0.f;
                v.w = ((unsigned)(g0 + 3) < (unsigned)N1) ? xrow[g0 + 3] : 0.f;
            }
            st4(xs, i, v);
        }
    }
    if (tid < 12)      stss(l1, tid, 0.f);
    if (tid < C::zt1)  stss(l1, 12 + C::span1 + tid, 0.f);
    bar_lgkm();

    // ---------- P2: Level 1, K=8 (single pass) ----------
    float hr1[8];
    const int tt1 = tid * 8;
    if (tt1 < C::span1) {
        float w[28];
#pragma unroll
        for (int m = 0; m < 7; ++m) {
            const float4 v = ld4(xs, tid * 4 + m);   // logical 2*tt1 = 16*tid
            w[4 * m + 0] = v.x; w[4 * m + 1] = v.y;
            w[4 * m + 2] = v.z; w[4 * m + 3] = v.w;
        }
        float a0[8];
#pragma unroll
        for (int k = 0; k < 8; ++k) { a0[k] = 0.f; hr1[k] = 0.f; }
#pragma unroll
        for (int l = 0; l < FILT_LEN; ++l) {
#pragma unroll
            for (int k = 0; k < 8; ++k) {
                const float v = w[2 * k + 2 + l];     // x idx 2t-10+l, window base 2t-12
                a0[k]  = fmaf(v, h0tap(l), a0[k]);
                hr1[k] = fmaf(v, h1tap(l), hr1[k]);
            }
        }
        if (tt1 + 8 <= C::span1) {                    // lo1 at logical 12+tt1
            st4(l1, 3 + 2 * tid, make_float4(a0[0], a0[1], a0[2], a0[3]));
            st4(l1, 4 + 2 * tid, make_float4(a0[4], a0[5], a0[6], a0[7]));
        } else {
#pragma unroll
            for (int k = 0; k < 8; ++k)
                if (tt1 + k < C::span1) stss(l1, 12 + tt1 + k, a0[k]);
        }
    }
    bar_lgkm();

    // ---------- P3: stash hi1; zero lo2 pads; Level 2, K=8 ----------
    if (tt1 < C::span1) {
        if (tt1 + 8 <= C::span1) {
            st4(xs, 2 * tid,     make_float4(hr1[0], hr1[1], hr1[2], hr1[3]));
            st4(xs, 2 * tid + 1, make_float4(hr1[4], hr1[5], hr1[6], hr1[7]));
        } else {
#pragma unroll
            for (int k = 0; k < 8; ++k)
                if (tt1 + k < C::span1) stss(xs, tt1 + k, hr1[k]);
        }
    }
    if (tid < 12)      stss(xs, LO2_OFF + tid, 0.f);
    if (tid < C::zt2)  stss(xs, LO2_OFF + 12 + C::span2 + tid, 0.f);

    {
        const int tt2 = tid * 8;
        if (tt2 < C::span2) {
            float w[28];
#pragma unroll
            for (int m = 0; m < 7; ++m) {   // l1 logical 2*tt2+ab2 = 16*tid+ab2
                const float4 v = ld4(l1, tid * 4 + (C::ab2 >> 2) + m);
                w[4 * m + 0] = v.x; w[4 * m + 1] = v.y;
                w[4 * m + 2] = v.z; w[4 * m + 3] = v.w;
            }
            float a0[8], a1[8];
#pragma unroll
            for (int k = 0; k < 8; ++k) { a0[k] = 0.f; a1[k] = 0.f; }
#pragma unroll
            for (int l = 0; l < FILT_LEN; ++l) {
#pragma unroll
                for (int k = 0; k < 8; ++k) {
                    const float v = w[2 * k + l + C::p2];
                    a0[k] = fmaf(v, h0tap(l), a0[k]);
                    a1[k] = fmaf(v, h1tap(l), a1[k]);
                }
            }
            if (tt2 + 8 <= C::span2) {
                // lo2 at logical LO2_OFF+12+tt2 -> f4 = 275 + 2*tid
                st4(xs, 275 + 2 * tid, make_float4(a0[0], a0[1], a0[2], a0[3]));
                st4(xs, 276 + 2 * tid, make_float4(a0[4], a0[5], a0[6], a0[7]));
                // hi2 stash at HB2_OFF+tt2 -> f4 = 416 + 2*tid
                st4(xs, 416 + 2 * tid, make_float4(a1[0], a1[1], a1[2], a1[3]));
                st4(xs, 417 + 2 * tid, make_float4(a1[4], a1[5], a1[6], a1[7]));
            } else {
#pragma unroll
                for (int k = 0; k < 8; ++k) {
                    if (tt2 + k < C::span2) {
                        stss(xs, LO2_OFF + 12 + tt2 + k, a0[k]);
                        stss(xs, HB2_OFF + tt2 + k, a1[k]);
                    }
                }
            }
        }
    }
    bar_lgkm();

    // ---------- P4: flush hi1+hi2 (nt); Level 3, K=8 -> stash in l1 ----------
    for (int i = C::o1s + tid; i < C::o1e; i += NTHR)
        ntst(hi1r + C::c1s + i, ldss(xs, i));
    for (int i = C::o2s + tid; i < C::o2e; i += NTHR)
        ntst(hi2r + C::c2s + i, ldss(xs, HB2_OFF + i));

    {
        const int tt3 = tid * 8;
        if (tt3 < C::span3) {
            float w[28];
#pragma unroll
            for (int m = 0; m < 7; ++m) {   // xs logical LO2_OFF+2*tt3+ab3
                const float4 v = ld4(xs, (LO2_OFF >> 2) + tid * 4 + (C::ab3 >> 2) + m);
                w[4 * m + 0] = v.x; w[4 * m + 1] = v.y;
                w[4 * m + 2] = v.z; w[4 * m + 3] = v.w;
            }
            float a0[8], a1[8];
#pragma unroll
            for (int k = 0; k < 8; ++k) { a0[k] = 0.f; a1[k] = 0.f; }
#pragma unroll
            for (int l = 0; l < FILT_LEN; ++l) {
#pragma unroll
                for (int k = 0; k < 8; ++k) {
                    const float v = w[2 * k + l + C::p3];
                    a0[k] = fmaf(v, h0tap(l), a0[k]);
                    a1[k] = fmaf(v, h1tap(l), a1[k]);
                }
            }
            if (tt3 + 8 <= C::span3) {
                st4(l1, 2 * tid,                     make_float4(a0[0], a0[1], a0[2], a0[3]));
                st4(l1, 2 * tid + 1,                 make_float4(a0[4], a0[5], a0[6], a0[7]));
                st4(l1, (HI3_OFF >> 2) + 2 * tid,     make_float4(a1[0], a1[1], a1[2], a1[3]));
                st4(l1, (HI3_OFF >> 2) + 2 * tid + 1, make_float4(a1[4], a1[5], a1[6], a1[7]));
            } else {
#pragma unroll
                for (int k = 0; k < 8; ++k) {
                    if (tt3 + k < C::span3) {
                        stss(l1, tt3 + k, a0[k]);
                        stss(l1, HI3_OFF + tt3 + k, a1[k]);
                    }
                }
            }
        }
    }
    bar_lgkm();   // lgkm-only: the hi1/hi2 global stores above need NO drain here

    // ---------- P5: flush lo3, hi3 (nt) ----------
    for (int i = tid; i < C::span3; i += NTHR) {
        ntst(lo3r + C::s3 + i, ldss(l1, i));
        ntst(hi3r + C::s3 + i, ldss(l1, HI3_OFF + i));
    }
}

__global__ __launch_bounds__(NTHR, 8) void dwt_fused_kernel(
    const float* __restrict__ x,
    float* __restrict__ lo3, float* __restrict__ hi1,
    float* __restrict__ hi2, float* __restrict__ hi3)
{
    __shared__ __align__(16) float xs[XCAP];
    __shared__ __align__(16) float l1[L1CAP];

    // XCD-aware remap. Dispatch linear id = blockIdx.x + 8*blockIdx.y; the CP
    // round-robins ids across the 8 XCDs, so id%8 = blockIdx.x selects the
    // XCD. Put all 8 tiles of one row on ONE XCD (dispatch-adjacent) so the
    // inter-tile staging halos are L2 hits instead of duplicate HBM fetches:
    //   row  = blockIdx.x*128 + (blockIdx.y>>3)   (XCD = row>>7, fixed per row)
    //   tile = blockIdx.y & 7                     (ids differ by 8: same XCD)
    // Bijection over (8 x 1024); perf heuristic only, never correctness (G16).
    const int tile = blockIdx.y & 7;
    const int row  = (int)blockIdx.x * 128 + ((int)blockIdx.y >> 3);
    const int tid = threadIdx.x;
    const float* xrow = x + (size_t)row * N1;
    float* lo3r = lo3 + (size_t)row * O3;
    float* hi1r = hi1 + (size_t)row * O1;
    float* hi2r = hi2 + (size_t)row * O2;
    float* hi3r = hi3 + (size_t)row * O3;

    switch (tile) {
        case 0:  body<0>(xrow, lo3r, hi1r, hi2r, hi3r, xs, l1, tid); break;
        case 1:  body<1>(xrow, lo3r, hi1r, hi2r, hi3r, xs, l1, tid); break;
        case 2:  body<2>(xrow, lo3r, hi1r, hi2r, hi3r, xs, l1, tid); break;
        case 3:  body<3>(xrow, lo3r, hi1r, hi2r, hi3r, xs, l1, tid); break;
        case 4:  body<4>(xrow, lo3r, hi1r, hi2r, hi3r, xs, l1, tid); break;
        case 5:  body<5>(xrow, lo3r, hi1r, hi2r, hi3r, xs, l1, tid); break;
        case 6:  body<6>(xrow, lo3r, hi1r, hi2r, hi3r, xs, l1, tid); break;
        default: body<7>(xrow, lo3r, hi1r, hi2r, hi3r, xs, l1, tid); break;
    }
}

extern "C" void kernel_launch(void* const* d_in, const int* in_sizes, int n_in,
                              void* d_out, int out_size, void* d_ws, size_t ws_size,
                              hipStream_t stream)
{
    const float* x = (const float*)d_in[0];
    float* out = (float*)d_out;

    // Output layout: (lo3, hi1, hi2, hi3) concatenated flat
    float* lo3 = out;
    float* hi1 = out + (size_t)ROWS * O3;
    float* hi2 = hi1 + (size_t)ROWS * O1;
    float* hi3 = hi2 + (size_t)ROWS * O2;

    dwt_fused_kernel<<<dim3(NBLK, ROWS), dim3(NTHR), 0, stream>>>(
        x, lo3, hi1, hi2, hi3);
}